// Round 8
// baseline (278.489 us; speedup 1.0000x reference)
//
#include <hip/hip_runtime.h>

typedef short s16x8 __attribute__((ext_vector_type(8)));
typedef short s16x4 __attribute__((ext_vector_type(4)));
typedef float f32x4 __attribute__((ext_vector_type(4)));
typedef float f32x16 __attribute__((ext_vector_type(16)));

__device__ __forceinline__ unsigned short f2bf(float f) {
  unsigned u = __float_as_uint(f);
  u += 0x7fffu + ((u >> 16) & 1u);
  return (unsigned short)(u >> 16);
}
__device__ __forceinline__ float bf2f(unsigned short h) {
  return __uint_as_float(((unsigned)h) << 16);
}

#define GLOAD_LDS16(g, l)                                          \
  __builtin_amdgcn_global_load_lds(                                \
      (const __attribute__((address_space(1))) void*)(g),          \
      (__attribute__((address_space(3))) void*)(l), 16, 0, 0)

// ---------------- prep kernels ----------------

__global__ __launch_bounds__(256) void cvt_x_bf16(const float* __restrict__ in,
                                                  unsigned short* __restrict__ out) {
  int i = (blockIdx.x * 256 + threadIdx.x) * 4;
  float4 v = *(const float4*)(in + i);
  ushort4 o;
  o.x = f2bf(v.x); o.y = f2bf(v.y); o.z = f2bf(v.z); o.w = f2bf(v.w);
  *(ushort4*)(out + i) = o;
}

// W[R][C] fp32 -> Wt[C][R] bf16
__global__ __launch_bounds__(256) void transpose_w(const float* __restrict__ W,
                                                   unsigned short* __restrict__ Wt,
                                                   int R, int C) {
  __shared__ float tile[32][33];
  int c0 = blockIdx.x * 32, r0 = blockIdx.y * 32;
  int x = threadIdx.x, ty = threadIdx.y;
  for (int yy = ty; yy < 32; yy += 8)
    tile[yy][x] = W[(size_t)(r0 + yy) * C + c0 + x];
  __syncthreads();
  for (int yy = ty; yy < 32; yy += 8)
    Wt[(size_t)(c0 + yy) * R + r0 + x] = f2bf(tile[x][yy]);
}

// ---------------- GEMM v6: 256x256 8-phase ----------------
// C[M][N] = A[M][K] * Bt[N][K]^T + bias. 512 threads = 8 waves (2M x 4N),
// wave tile 128x64, 32x32x16 MFMA, acc[4][2] f32x16.
// K-tile = BK=32. LDS: FOUR K-tile buffers (4 x (A 16KB + B 16KB) = 128KB),
// 3-tile-deep prefetch with counted vmcnt (T4): gate before tile t is
//   vmcnt(8): tile t's 4 gload_lds landed; tiles t+1,t+2 (8 loads) in flight
//   s_barrier: all waves passed their own vmcnt -> tile t visible to all;
//              all waves finished reading buf[(t-1)&3] -> staging buf[(t+3)&3]
//              (same buffer) after this barrier is WAR-safe.
// Per tile: 2 phases (k-step 0/1), each = {6 ds_read_b128 || 2 gload_lds ->
// barrier -> lgkmcnt(0)+sched_barrier -> setprio(1) 8 MFMA setprio(0) ->
// barrier} — the m196-proven fine interleave; loads span phases, vmcnt never
// drains to 0 until the final tile.
// LDS layout/swizzle identical to the r5-proven one: [256][32] shorts, chunk
// c ^= ((row>>1)&3) via pre-swizzled global source col; read rx=((lm>>1)&3)<<4
// (wave-row bases are multiples of 32, so bank behavior is unchanged).
// MODE 0: f32 out. MODE 1: bf16; n0>=2048 blocks (V third of QKV) store
// TRANSPOSED direct to vtr[(b*16+h)*64+d][tok].

template <int MODE>
__global__ __launch_bounds__(512, 2) void gemm_bt(const unsigned short* __restrict__ A,
                                                  const unsigned short* __restrict__ Bt,
                                                  const float* __restrict__ bias,
                                                  void* __restrict__ Cout,
                                                  unsigned short* __restrict__ vtr,
                                                  int M, int N, int K) {
  __shared__ __align__(16) unsigned short As[4][256 * 32];
  __shared__ __align__(16) unsigned short Bs[4][256 * 32];

  const int tid  = threadIdx.x;
  const int lane = tid & 63;
  const int w    = tid >> 6;    // 0..7
  const int lm   = lane & 31;   // frag row/col within 32
  const int l5   = lane >> 5;   // k-half selector
  const int wr   = w >> 2;      // 0..1: M rows [wr*128, wr*128+128)
  const int wc   = w & 3;       // 0..3: N cols [wc*64, wc*64+64)
  const int m0   = blockIdx.x * 256;  // x = m: XCD-stable A tiles
  const int n0   = blockIdx.y * 256;

  f32x16 acc[4][2];
  for (int i = 0; i < 4; i++)
    for (int j = 0; j < 2; j++)
      for (int r = 0; r < 16; r++) acc[i][j][r] = 0.f;

  const int srow = tid >> 2;                                // staging row 0..127
  const int scb  = (((tid & 3) ^ ((srow >> 1) & 3)) * 8);   // pre-swizzled source col
  const unsigned short* Ap = A  + (size_t)(m0 + srow) * K + scb;
  const unsigned short* Bp = Bt + (size_t)(n0 + srow) * K + scb;

  // unit0 = rows 0..127, unit1 = rows 128..255; dest linear, 1KB per wave
#define STAGE_A(bb, t)                                                    \
  do {                                                                    \
    GLOAD_LDS16(Ap + (t) * 32, &As[bb][w * 512]);                         \
    GLOAD_LDS16(Ap + (size_t)128 * K + (t) * 32, &As[bb][4096 + w * 512]);\
  } while (0)
#define STAGE_B(bb, t)                                                    \
  do {                                                                    \
    GLOAD_LDS16(Bp + (t) * 32, &Bs[bb][w * 512]);                         \
    GLOAD_LDS16(Bp + (size_t)128 * K + (t) * 32, &Bs[bb][4096 + w * 512]);\
  } while (0)

  const int rx = ((lm >> 1) & 3) << 4;  // read-side XOR (bytes)
  const int nt = K >> 5;                // K-tiles (32 for K=1024)

  STAGE_A(0, 0); STAGE_B(0, 0);
  STAGE_A(1, 1); STAGE_B(1, 1);
  STAGE_A(2, 2); STAGE_B(2, 2);

  for (int t = 0; t < nt; t++) {
    // ---- gate: tile t landed; up to 8 newer loads stay in flight
    if (t + 2 < nt)
      asm volatile("s_waitcnt vmcnt(8)" ::: "memory");
    else if (t + 1 < nt)
      asm volatile("s_waitcnt vmcnt(4)" ::: "memory");
    else
      asm volatile("s_waitcnt vmcnt(0)" ::: "memory");
    __builtin_amdgcn_s_barrier();
    __builtin_amdgcn_sched_barrier(0);

    const char* Ab = (const char*)As[t & 3];
    const char* Bb = (const char*)Bs[t & 3];
    const int  nb = (t + 3) & 3;
    const bool st = (t + 3) < nt;

    // ---- phase 1: k-step 0
    s16x8 a0[4], b0[2];
    for (int i = 0; i < 4; i++)
      a0[i] = *(const s16x8*)(Ab + (wr * 128 + i * 32 + lm) * 64 + ((l5 * 16) ^ rx));
    for (int j = 0; j < 2; j++)
      b0[j] = *(const s16x8*)(Bb + (wc * 64 + j * 32 + lm) * 64 + ((l5 * 16) ^ rx));
    if (st) STAGE_A(nb, t + 3);
    __builtin_amdgcn_s_barrier();
    asm volatile("s_waitcnt lgkmcnt(0)" ::: "memory");
    __builtin_amdgcn_sched_barrier(0);
    __builtin_amdgcn_s_setprio(1);
    for (int i = 0; i < 4; i++)
      for (int j = 0; j < 2; j++)
        acc[i][j] = __builtin_amdgcn_mfma_f32_32x32x16_bf16(a0[i], b0[j], acc[i][j], 0, 0, 0);
    __builtin_amdgcn_s_setprio(0);
    __builtin_amdgcn_s_barrier();
    __builtin_amdgcn_sched_barrier(0);

    // ---- phase 2: k-step 1
    s16x8 a1[4], b1[2];
    for (int i = 0; i < 4; i++)
      a1[i] = *(const s16x8*)(Ab + (wr * 128 + i * 32 + lm) * 64 + ((32 + l5 * 16) ^ rx));
    for (int j = 0; j < 2; j++)
      b1[j] = *(const s16x8*)(Bb + (wc * 64 + j * 32 + lm) * 64 + ((32 + l5 * 16) ^ rx));
    if (st) STAGE_B(nb, t + 3);
    __builtin_amdgcn_s_barrier();
    asm volatile("s_waitcnt lgkmcnt(0)" ::: "memory");
    __builtin_amdgcn_sched_barrier(0);
    __builtin_amdgcn_s_setprio(1);
    for (int i = 0; i < 4; i++)
      for (int j = 0; j < 2; j++)
        acc[i][j] = __builtin_amdgcn_mfma_f32_32x32x16_bf16(a1[i], b1[j], acc[i][j], 0, 0, 0);
    __builtin_amdgcn_s_setprio(0);
    // trailing barrier of phase 2 == next iteration's gate barrier
  }
#undef STAGE_A
#undef STAGE_B

  // epilogue: C/D layout col=lane&31, row=(r&3)+8*(r>>2)+4*l5
  if (MODE == 1 && n0 >= 2048) {
    // V third: store transposed to vtr[b*1024 + (col-2048)][token]
    const int bidx = m0 >> 11;  // batch (m0 multiple of 256; 2048%256==0)
    for (int j = 0; j < 2; j++) {
      int col = n0 + wc * 64 + j * 32 + lm;
      float bc = bias[col];
      size_t vrow = (size_t)((bidx << 10) + (col - 2048)) * 2048;
      for (int i = 0; i < 4; i++) {
        int tb = (m0 & 2047) + wr * 128 + i * 32 + l5 * 4;
        for (int g = 0; g < 4; g++) {
          ushort4 o;
          o.x = f2bf(acc[i][j][g * 4 + 0] + bc);
          o.y = f2bf(acc[i][j][g * 4 + 1] + bc);
          o.z = f2bf(acc[i][j][g * 4 + 2] + bc);
          o.w = f2bf(acc[i][j][g * 4 + 3] + bc);
          *(ushort4*)(vtr + vrow + tb + 8 * g) = o;
        }
      }
    }
  } else {
    for (int j = 0; j < 2; j++) {
      int col = n0 + wc * 64 + j * 32 + lm;
      float bc = bias[col];
      for (int i = 0; i < 4; i++) {
        int rowb = m0 + wr * 128 + i * 32 + l5 * 4;
        for (int r = 0; r < 16; r++) {
          int row = rowb + (r & 3) + 8 * (r >> 2);
          float v = acc[i][j][r] + bc;
          if (MODE == 1)
            ((unsigned short*)Cout)[(size_t)row * N + col] = f2bf(v);
          else
            ((float*)Cout)[(size_t)row * N + col] = v;
        }
      }
    }
  }
}

// ---------------- flash attention v11 (unchanged from r6) ----------------
// 4 waves x 32 q, all-K32 MFMA path, dbuf gload_lds prefetch, kt-loop
// unrolled x2, v_cvt_pk_bf16_f32 P-pack, setprio around MFMA clusters.

__global__ __launch_bounds__(256, 4) void attn_flash(const unsigned short* __restrict__ qkv,
                                                     const unsigned short* __restrict__ vt,
                                                     unsigned short* __restrict__ y) {
  const int T = 2048, C3 = 3072;
  const int bh = blockIdx.x & 63;
  const int qt = blockIdx.x >> 6;
  const int b  = bh >> 4;
  const int h  = bh & 15;
  const int q0 = qt * 128;

  const int tid  = threadIdx.x;
  const int lane = tid & 63;
  const int w    = tid >> 6;  // 0..3, wave owns q rows q0 + w*32 + [0,32)
  const int lr   = lane & 15;
  const int quad = lane >> 4;

  __shared__ __align__(16) unsigned short Ks[2][64][64];  // keys x d, swizzled, K-row-permuted
  __shared__ __align__(16) unsigned short Vs[2][64][64];  // d x keys (V^T), swizzled

  // Q as B-operand: qf[j][c] covers q rows w*32 + j*16 + lr, d-chunk c.
  s16x8 qf[2][2];
  const float QSC = 0.18033688f;  // log2(e)/sqrt(64)
  for (int j = 0; j < 2; j++)
    for (int c = 0; c < 2; c++) {
      const unsigned short* qp =
          qkv + (size_t)(b * T + q0 + w * 32 + j * 16 + lr) * C3 + h * 64 + c * 32 + quad * 8;
      s16x8 t = *(const s16x8*)qp;
      s16x8 o;
      for (int e = 0; e < 8; e++)
        o[e] = (short)f2bf(bf2f((unsigned short)t[e]) * QSC);
      qf[j][c] = o;
    }

  s16x8 ones;
  for (int e = 0; e < 8; e++) ones[e] = (short)0x3F80;  // bf16 1.0

  f32x4 O[2][4];   // [q-subtile j][d-tile]; row=q(quad*4+r), col=d(lr)
  f32x4 Lacc[2];   // row-sum accumulator, same row layout as O
  for (int j = 0; j < 2; j++) {
    for (int dt = 0; dt < 4; dt++) O[j][dt] = f32x4{0.f, 0.f, 0.f, 0.f};
    Lacc[j] = f32x4{0.f, 0.f, 0.f, 0.f};
  }

  const int srow = tid >> 3;                       // 0..31
  // pre-swizzled global source col (shorts): lane slot (l&7) XOR row&7
  const int scol = (((tid & 7) ^ (srow & 7)) * 8);
  // K-row permutation within each 32-key chunk: storage row -> key
  const int kperm = (((srow & 12) << 1) | ((srow >> 4) << 2) | (srow & 3));

  const unsigned short* kbase = qkv + (size_t)(b * T) * C3 + 1024 + (size_t)h * 64;
  const unsigned short* vbase = vt + (size_t)(bh * 64) * 2048;
  const unsigned short* kp0 = kbase + (size_t)(kperm)      * C3 + scol;  // rows 0..31
  const unsigned short* kp1 = kbase + (size_t)(32 + kperm) * C3 + scol;  // rows 32..63
  const unsigned short* vp0 = vbase + (size_t)(srow)      * 2048 + scol;
  const unsigned short* vp1 = vbase + (size_t)(srow + 32) * 2048 + scol;

#define STAGE_KV(bb)                                                         \
  do {                                                                       \
    GLOAD_LDS16(kp0, &Ks[bb][w * 8][0]);                                     \
    GLOAD_LDS16(kp1, &Ks[bb][w * 8 + 32][0]);                                \
    GLOAD_LDS16(vp0, &Vs[bb][w * 8][0]);                                     \
    GLOAD_LDS16(vp1, &Vs[bb][w * 8 + 32][0]);                                \
    kp0 += (size_t)64 * C3; kp1 += (size_t)64 * C3;                          \
    vp0 += 64; vp1 += 64;                                                    \
  } while (0)

  const int rswz = (lr & 7) << 4;  // read-side XOR (row&7 == lr&7 for all reads)

#define COMPUTE(bb)                                                              \
  do {                                                                           \
    const char* KsB = (const char*)&Ks[bb][0][0];                                \
    const char* VsB = (const char*)&Vs[bb][0][0];                                \
    for (int ch = 0; ch < 2; ch++) {                                             \
      const char* krowA = KsB + (ch * 32 + lr) * 128;                            \
      const char* krowB = KsB + (ch * 32 + 16 + lr) * 128;                       \
      s16x8 kA0 = *(const s16x8*)(krowA + ((quad * 16) ^ rswz));                 \
      s16x8 kA1 = *(const s16x8*)(krowA + ((64 + quad * 16) ^ rswz));            \
      s16x8 kB0 = *(const s16x8*)(krowB + ((quad * 16) ^ rswz));                 \
      s16x8 kB1 = *(const s16x8*)(krowB + ((64 + quad * 16) ^ rswz));            \
      s16x8 vf[4];                                                               \
      for (int dt = 0; dt < 4; dt++)                                             \
        vf[dt] = *(const s16x8*)(VsB + (dt * 16 + lr) * 128 +                    \
                                 ((ch * 64 + quad * 16) ^ rswz));                \
      for (int j = 0; j < 2; j++) {                                              \
        f32x4 Sa = f32x4{0.f, 0.f, 0.f, 0.f};                                    \
        f32x4 Sb = f32x4{0.f, 0.f, 0.f, 0.f};                                    \
        __builtin_amdgcn_s_setprio(1);                                           \
        Sa = __builtin_amdgcn_mfma_f32_16x16x32_bf16(kA0, qf[j][0], Sa, 0, 0, 0);\
        Sa = __builtin_amdgcn_mfma_f32_16x16x32_bf16(kA1, qf[j][1], Sa, 0, 0, 0);\
        Sb = __builtin_amdgcn_mfma_f32_16x16x32_bf16(kB0, qf[j][0], Sb, 0, 0, 0);\
        Sb = __builtin_amdgcn_mfma_f32_16x16x32_bf16(kB1, qf[j][1], Sb, 0, 0, 0);\
        __builtin_amdgcn_s_setprio(0);                                           \
        float p0 = __builtin_amdgcn_exp2f(Sa[0]);                                \
        float p1 = __builtin_amdgcn_exp2f(Sa[1]);                                \
        float p2 = __builtin_amdgcn_exp2f(Sa[2]);                                \
        float p3 = __builtin_amdgcn_exp2f(Sa[3]);                                \
        float p4 = __builtin_amdgcn_exp2f(Sb[0]);                                \
        float p5 = __builtin_amdgcn_exp2f(Sb[1]);                                \
        float p6 = __builtin_amdgcn_exp2f(Sb[2]);                                \
        float p7 = __builtin_amdgcn_exp2f(Sb[3]);                                \
        union { unsigned u[4]; s16x8 v; } pk;                                    \
        asm("v_cvt_pk_bf16_f32 %0, %1, %2" : "=v"(pk.u[0]) : "v"(p0), "v"(p1));  \
        asm("v_cvt_pk_bf16_f32 %0, %1, %2" : "=v"(pk.u[1]) : "v"(p2), "v"(p3));  \
        asm("v_cvt_pk_bf16_f32 %0, %1, %2" : "=v"(pk.u[2]) : "v"(p4), "v"(p5));  \
        asm("v_cvt_pk_bf16_f32 %0, %1, %2" : "=v"(pk.u[3]) : "v"(p6), "v"(p7));  \
        __builtin_amdgcn_s_setprio(1);                                           \
        Lacc[j] = __builtin_amdgcn_mfma_f32_16x16x32_bf16(pk.v, ones, Lacc[j],   \
                                                          0, 0, 0);              \
        for (int dt = 0; dt < 4; dt++)                                           \
          O[j][dt] = __builtin_amdgcn_mfma_f32_16x16x32_bf16(pk.v, vf[dt],       \
                                                             O[j][dt], 0, 0, 0); \
        __builtin_amdgcn_s_setprio(0);                                           \
      }                                                                          \
    }                                                                            \
  } while (0)

  STAGE_KV(0);
  for (int kt2 = 0; kt2 < 16; kt2++) {
    __syncthreads();   // buf0's loads visible; all waves done reading buf1
    STAGE_KV(1);       // tile 2*kt2+1 (always valid)
    COMPUTE(0);        // tile 2*kt2
    __syncthreads();   // buf1's loads visible; all waves done reading buf0
    if (kt2 < 15) STAGE_KV(0);  // tile 2*kt2+2
    COMPUTE(1);        // tile 2*kt2+1
  }
#undef STAGE_KV
#undef COMPUTE

  // epilogue: Lacc rows align with O rows -> no cross-lane traffic
  for (int j = 0; j < 2; j++) {
    for (int r = 0; r < 4; r++) {
      float inv = 1.f / Lacc[j][r];
      int row = b * T + q0 + w * 32 + j * 16 + quad * 4 + r;
      for (int dt = 0; dt < 4; dt++) {
        int col = h * 64 + dt * 16 + lr;
        y[(size_t)row * 1024 + col] = f2bf(O[j][dt][r] * inv);
      }
    }
  }
}

// ---------------- launch ----------------

extern "C" void kernel_launch(void* const* d_in, const int* in_sizes, int n_in,
                              void* d_out, int out_size, void* d_ws, size_t ws_size,
                              hipStream_t stream) {
  const float* x  = (const float*)d_in[0];
  const float* Wa = (const float*)d_in[1];
  const float* ba = (const float*)d_in[2];
  const float* Wp = (const float*)d_in[3];
  const float* bp = (const float*)d_in[4];
  float* out = (float*)d_out;

  char* ws = (char*)d_ws;
  unsigned short* xb  = (unsigned short*)ws;                 // 16 MB: x bf16, later y
  unsigned short* Wat = (unsigned short*)(ws + 16777216);    // 6 MB
  unsigned short* Wpt = (unsigned short*)(ws + 23068672);    // 2 MB
  unsigned short* qkv = (unsigned short*)(ws + 25165824);    // 48 MB (V third unused)
  unsigned short* vtr = (unsigned short*)(ws + 75497472);    // 16 MB

  cvt_x_bf16<<<8192, 256, 0, stream>>>(x, xb);
  transpose_w<<<dim3(96, 32), dim3(32, 8), 0, stream>>>(Wa, Wat, 1024, 3072);
  transpose_w<<<dim3(32, 32), dim3(32, 8), 0, stream>>>(Wp, Wpt, 1024, 1024);

  // 256^2 8-phase gemm: QKV grid 32x12 (V third straight to vtr, transposed)
  gemm_bt<1><<<dim3(32, 12), 512, 0, stream>>>(xb, Wat, ba, qkv, vtr, 8192, 3072, 1024);

  attn_flash<<<1024, 256, 0, stream>>>(qkv, vtr, xb);

  gemm_bt<0><<<dim3(32, 4), 512, 0, stream>>>(xb, Wpt, bp, out, nullptr, 8192, 1024, 1024);
}

// Round 9
// 271.604 us; speedup vs baseline: 1.0254x; 1.0254x over previous
//
#include <hip/hip_runtime.h>

typedef short s16x8 __attribute__((ext_vector_type(8)));
typedef short s16x4 __attribute__((ext_vector_type(4)));
typedef float f32x4 __attribute__((ext_vector_type(4)));
typedef float f32x16 __attribute__((ext_vector_type(16)));

__device__ __forceinline__ unsigned short f2bf(float f) {
  unsigned u = __float_as_uint(f);
  u += 0x7fffu + ((u >> 16) & 1u);
  return (unsigned short)(u >> 16);
}
__device__ __forceinline__ float bf2f(unsigned short h) {
  return __uint_as_float(((unsigned)h) << 16);
}

#define GLOAD_LDS16(g, l)                                          \
  __builtin_amdgcn_global_load_lds(                                \
      (const __attribute__((address_space(1))) void*)(g),          \
      (__attribute__((address_space(3))) void*)(l), 16, 0, 0)

// ---------------- prep kernels ----------------

__global__ __launch_bounds__(256) void cvt_x_bf16(const float* __restrict__ in,
                                                  unsigned short* __restrict__ out) {
  int i = (blockIdx.x * 256 + threadIdx.x) * 4;
  float4 v = *(const float4*)(in + i);
  ushort4 o;
  o.x = f2bf(v.x); o.y = f2bf(v.y); o.z = f2bf(v.z); o.w = f2bf(v.w);
  *(ushort4*)(out + i) = o;
}

// W[R][C] fp32 -> Wt[C][R] bf16
__global__ __launch_bounds__(256) void transpose_w(const float* __restrict__ W,
                                                   unsigned short* __restrict__ Wt,
                                                   int R, int C) {
  __shared__ float tile[32][33];
  int c0 = blockIdx.x * 32, r0 = blockIdx.y * 32;
  int x = threadIdx.x, ty = threadIdx.y;
  for (int yy = ty; yy < 32; yy += 8)
    tile[yy][x] = W[(size_t)(r0 + yy) * C + c0 + x];
  __syncthreads();
  for (int yy = ty; yy < 32; yy += 8)
    Wt[(size_t)(c0 + yy) * R + r0 + x] = f2bf(tile[x][yy]);
}

// ---------------- GEMM v7: 128x128 tile, BK=64, 2-buf desync ----------------
// C[M][N] = A[M][K] * Bt[N][K]^T + bias. 256 threads = 4 waves (2x2), wave
// tile 64x64, 32x32x16 MFMA, acc[2][2].
// BK=64: LDS = 2 bufs x (A[128][64] + B[128][64]) bf16 = 64KB -> 2 desynced
// blocks/CU (the r8 1-block/CU mistake undone). Per K-tile: ONE barrier +
// ONE stage burst (8 gload_lds/thread) + 16 ds_read_b128 + 16 MFMA/wave —
// halves the per-K barrier/drain/stage overhead of the r6/r7 BK=32 loop and
// doubles MFMA per batch, without touching the proven 2-phase skeleton.
// LDS rows are 128B; swizzle = attn's measured-zero-conflict one: 16B chunk c
// of row r stored at slot c^(r&7), staged via pre-swizzled GLOBAL source
// (gload_lds dest linear: instr i of wave w covers rows (w+i*4)*8..+8, lane
// l -> row +(l>>3), slot l&7, source chunk (l&7)^(l>>3)). Read: k-step k,
// half l5 -> slot (2k+l5)^(lm&7): per 16-lane quarter all 8 slots x2 = the
// free 2-access/bank b128 floor.
// Grids tail-perfect: QKV 64x24=1536=6x256, proj 64x8=512=2x256.
// MODE 0: f32 out. MODE 1: bf16; n0>=2048 blocks (V third of QKV) store
// TRANSPOSED direct to vtr[(b*16+h)*64+d][tok] (no transpose_v dispatch).

template <int MODE>
__global__ __launch_bounds__(256) void gemm_bt(const unsigned short* __restrict__ A,
                                               const unsigned short* __restrict__ Bt,
                                               const float* __restrict__ bias,
                                               void* __restrict__ Cout,
                                               unsigned short* __restrict__ vtr,
                                               int M, int N, int K) {
  __shared__ __align__(16) unsigned short As[2][128 * 64];
  __shared__ __align__(16) unsigned short Bs[2][128 * 64];

  const int tid  = threadIdx.x;
  const int lane = tid & 63;
  const int w    = tid >> 6;    // 0..3
  const int lm   = lane & 31;   // frag row/col within 32
  const int l5   = lane >> 5;   // k-half selector
  const int wm   = (w >> 1) * 64;
  const int wn   = (w & 1) * 64;
  const int m0   = blockIdx.x * 128;  // x = m: XCD-stable A tiles
  const int n0   = blockIdx.y * 128;

  f32x16 acc[2][2];
  for (int i = 0; i < 2; i++)
    for (int j = 0; j < 2; j++)
      for (int r = 0; r < 16; r++) acc[i][j][r] = 0.f;

  // staging: lane l covers row (w+i*4)*8 + (l>>3), dest slot l&7,
  // source chunk (l&7)^(l>>3)  (row&7 == l>>3 since row bases are mult of 8)
  const int lr3 = lane >> 3;                 // 0..7
  const int sch = ((lane & 7) ^ lr3) * 8;    // pre-swizzled source col (shorts)
  const unsigned short* Ap = A  + (size_t)(m0 + w * 8 + lr3) * K + sch;
  const unsigned short* Bp = Bt + (size_t)(n0 + w * 8 + lr3) * K + sch;

#define STAGE_G(bb, t)                                                        \
  do {                                                                        \
    for (int i = 0; i < 4; i++) {                                             \
      GLOAD_LDS16(Ap + (size_t)(i * 32) * K + (t) * 64, &As[bb][(w + i * 4) * 512]); \
      GLOAD_LDS16(Bp + (size_t)(i * 32) * K + (t) * 64, &Bs[bb][(w + i * 4) * 512]); \
    }                                                                         \
  } while (0)

  const int nt = K >> 6;  // 16 for K=1024

  STAGE_G(0, 0);
  int cur = 0;
  for (int t = 0; t < nt; t++) {
    __syncthreads();  // drains vmcnt: tile t landed; all waves done with buf cur^1
    if (t + 1 < nt) STAGE_G(cur ^ 1, t + 1);

    const char* Ab = (const char*)As[cur];
    const char* Bb = (const char*)Bs[cur];
    s16x8 af[2][4], bfr[2][4];
    for (int i = 0; i < 2; i++) {
      int row = wm + i * 32 + lm;
      const char* rp = Ab + row * 128;
      for (int k = 0; k < 4; k++)
        af[i][k] = *(const s16x8*)(rp + (((2 * k + l5) ^ (lm & 7)) * 16));
    }
    for (int j = 0; j < 2; j++) {
      int row = wn + j * 32 + lm;
      const char* rp = Bb + row * 128;
      for (int k = 0; k < 4; k++)
        bfr[j][k] = *(const s16x8*)(rp + (((2 * k + l5) ^ (lm & 7)) * 16));
    }
    __builtin_amdgcn_s_setprio(1);
    for (int k = 0; k < 4; k++)
      for (int i = 0; i < 2; i++)
        for (int j = 0; j < 2; j++)
          acc[i][j] = __builtin_amdgcn_mfma_f32_32x32x16_bf16(af[i][k], bfr[j][k],
                                                              acc[i][j], 0, 0, 0);
    __builtin_amdgcn_s_setprio(0);
    cur ^= 1;
  }
#undef STAGE_G

  // epilogue: C/D layout col=lane&31, row=(r&3)+8*(r>>2)+4*l5
  if (MODE == 1 && n0 >= 2048) {
    // V third: store transposed to vtr[b*1024 + (col-2048)][token]
    const int bidx = m0 >> 11;  // batch (m0 multiple of 128)
    for (int j = 0; j < 2; j++) {
      int col = n0 + wn + j * 32 + lm;
      float bc = bias[col];
      size_t vrow = (size_t)((bidx << 10) + (col - 2048)) * 2048;
      for (int i = 0; i < 2; i++) {
        int tb = (m0 & 2047) + wm + i * 32 + l5 * 4;
        for (int g = 0; g < 4; g++) {
          ushort4 o;
          o.x = f2bf(acc[i][j][g * 4 + 0] + bc);
          o.y = f2bf(acc[i][j][g * 4 + 1] + bc);
          o.z = f2bf(acc[i][j][g * 4 + 2] + bc);
          o.w = f2bf(acc[i][j][g * 4 + 3] + bc);
          *(ushort4*)(vtr + vrow + tb + 8 * g) = o;
        }
      }
    }
  } else {
    for (int j = 0; j < 2; j++) {
      int col = n0 + wn + j * 32 + lm;
      float bc = bias[col];
      for (int i = 0; i < 2; i++) {
        int rowb = m0 + wm + i * 32 + l5 * 4;
        for (int r = 0; r < 16; r++) {
          int row = rowb + (r & 3) + 8 * (r >> 2);
          float v = acc[i][j][r] + bc;
          if (MODE == 1)
            ((unsigned short*)Cout)[(size_t)row * N + col] = f2bf(v);
          else
            ((float*)Cout)[(size_t)row * N + col] = v;
        }
      }
    }
  }
}

// ---------------- flash attention v11 (unchanged) ----------------
// 4 waves x 32 q, all-K32 MFMA path, dbuf gload_lds prefetch, kt-loop
// unrolled x2, v_cvt_pk_bf16_f32 P-pack, setprio around MFMA clusters.

__global__ __launch_bounds__(256, 4) void attn_flash(const unsigned short* __restrict__ qkv,
                                                     const unsigned short* __restrict__ vt,
                                                     unsigned short* __restrict__ y) {
  const int T = 2048, C3 = 3072;
  const int bh = blockIdx.x & 63;
  const int qt = blockIdx.x >> 6;
  const int b  = bh >> 4;
  const int h  = bh & 15;
  const int q0 = qt * 128;

  const int tid  = threadIdx.x;
  const int lane = tid & 63;
  const int w    = tid >> 6;  // 0..3, wave owns q rows q0 + w*32 + [0,32)
  const int lr   = lane & 15;
  const int quad = lane >> 4;

  __shared__ __align__(16) unsigned short Ks[2][64][64];  // keys x d, swizzled, K-row-permuted
  __shared__ __align__(16) unsigned short Vs[2][64][64];  // d x keys (V^T), swizzled

  // Q as B-operand: qf[j][c] covers q rows w*32 + j*16 + lr, d-chunk c.
  s16x8 qf[2][2];
  const float QSC = 0.18033688f;  // log2(e)/sqrt(64)
  for (int j = 0; j < 2; j++)
    for (int c = 0; c < 2; c++) {
      const unsigned short* qp =
          qkv + (size_t)(b * T + q0 + w * 32 + j * 16 + lr) * C3 + h * 64 + c * 32 + quad * 8;
      s16x8 t = *(const s16x8*)qp;
      s16x8 o;
      for (int e = 0; e < 8; e++)
        o[e] = (short)f2bf(bf2f((unsigned short)t[e]) * QSC);
      qf[j][c] = o;
    }

  s16x8 ones;
  for (int e = 0; e < 8; e++) ones[e] = (short)0x3F80;  // bf16 1.0

  f32x4 O[2][4];   // [q-subtile j][d-tile]; row=q(quad*4+r), col=d(lr)
  f32x4 Lacc[2];   // row-sum accumulator, same row layout as O
  for (int j = 0; j < 2; j++) {
    for (int dt = 0; dt < 4; dt++) O[j][dt] = f32x4{0.f, 0.f, 0.f, 0.f};
    Lacc[j] = f32x4{0.f, 0.f, 0.f, 0.f};
  }

  const int srow = tid >> 3;                       // 0..31
  // pre-swizzled global source col (shorts): lane slot (l&7) XOR row&7
  const int scol = (((tid & 7) ^ (srow & 7)) * 8);
  // K-row permutation within each 32-key chunk: storage row -> key
  const int kperm = (((srow & 12) << 1) | ((srow >> 4) << 2) | (srow & 3));

  const unsigned short* kbase = qkv + (size_t)(b * T) * C3 + 1024 + (size_t)h * 64;
  const unsigned short* vbase = vt + (size_t)(bh * 64) * 2048;
  const unsigned short* kp0 = kbase + (size_t)(kperm)      * C3 + scol;  // rows 0..31
  const unsigned short* kp1 = kbase + (size_t)(32 + kperm) * C3 + scol;  // rows 32..63
  const unsigned short* vp0 = vbase + (size_t)(srow)      * 2048 + scol;
  const unsigned short* vp1 = vbase + (size_t)(srow + 32) * 2048 + scol;

#define STAGE_KV(bb)                                                         \
  do {                                                                       \
    GLOAD_LDS16(kp0, &Ks[bb][w * 8][0]);                                     \
    GLOAD_LDS16(kp1, &Ks[bb][w * 8 + 32][0]);                                \
    GLOAD_LDS16(vp0, &Vs[bb][w * 8][0]);                                     \
    GLOAD_LDS16(vp1, &Vs[bb][w * 8 + 32][0]);                                \
    kp0 += (size_t)64 * C3; kp1 += (size_t)64 * C3;                          \
    vp0 += 64; vp1 += 64;                                                    \
  } while (0)

  const int rswz = (lr & 7) << 4;  // read-side XOR (row&7 == lr&7 for all reads)

#define COMPUTE(bb)                                                              \
  do {                                                                           \
    const char* KsB = (const char*)&Ks[bb][0][0];                                \
    const char* VsB = (const char*)&Vs[bb][0][0];                                \
    for (int ch = 0; ch < 2; ch++) {                                             \
      const char* krowA = KsB + (ch * 32 + lr) * 128;                            \
      const char* krowB = KsB + (ch * 32 + 16 + lr) * 128;                       \
      s16x8 kA0 = *(const s16x8*)(krowA + ((quad * 16) ^ rswz));                 \
      s16x8 kA1 = *(const s16x8*)(krowA + ((64 + quad * 16) ^ rswz));            \
      s16x8 kB0 = *(const s16x8*)(krowB + ((quad * 16) ^ rswz));                 \
      s16x8 kB1 = *(const s16x8*)(krowB + ((64 + quad * 16) ^ rswz));            \
      s16x8 vf[4];                                                               \
      for (int dt = 0; dt < 4; dt++)                                             \
        vf[dt] = *(const s16x8*)(VsB + (dt * 16 + lr) * 128 +                    \
                                 ((ch * 64 + quad * 16) ^ rswz));                \
      for (int j = 0; j < 2; j++) {                                              \
        f32x4 Sa = f32x4{0.f, 0.f, 0.f, 0.f};                                    \
        f32x4 Sb = f32x4{0.f, 0.f, 0.f, 0.f};                                    \
        __builtin_amdgcn_s_setprio(1);                                           \
        Sa = __builtin_amdgcn_mfma_f32_16x16x32_bf16(kA0, qf[j][0], Sa, 0, 0, 0);\
        Sa = __builtin_amdgcn_mfma_f32_16x16x32_bf16(kA1, qf[j][1], Sa, 0, 0, 0);\
        Sb = __builtin_amdgcn_mfma_f32_16x16x32_bf16(kB0, qf[j][0], Sb, 0, 0, 0);\
        Sb = __builtin_amdgcn_mfma_f32_16x16x32_bf16(kB1, qf[j][1], Sb, 0, 0, 0);\
        __builtin_amdgcn_s_setprio(0);                                           \
        float p0 = __builtin_amdgcn_exp2f(Sa[0]);                                \
        float p1 = __builtin_amdgcn_exp2f(Sa[1]);                                \
        float p2 = __builtin_amdgcn_exp2f(Sa[2]);                                \
        float p3 = __builtin_amdgcn_exp2f(Sa[3]);                                \
        float p4 = __builtin_amdgcn_exp2f(Sb[0]);                                \
        float p5 = __builtin_amdgcn_exp2f(Sb[1]);                                \
        float p6 = __builtin_amdgcn_exp2f(Sb[2]);                                \
        float p7 = __builtin_amdgcn_exp2f(Sb[3]);                                \
        union { unsigned u[4]; s16x8 v; } pk;                                    \
        asm("v_cvt_pk_bf16_f32 %0, %1, %2" : "=v"(pk.u[0]) : "v"(p0), "v"(p1));  \
        asm("v_cvt_pk_bf16_f32 %0, %1, %2" : "=v"(pk.u[1]) : "v"(p2), "v"(p3));  \
        asm("v_cvt_pk_bf16_f32 %0, %1, %2" : "=v"(pk.u[2]) : "v"(p4), "v"(p5));  \
        asm("v_cvt_pk_bf16_f32 %0, %1, %2" : "=v"(pk.u[3]) : "v"(p6), "v"(p7));  \
        __builtin_amdgcn_s_setprio(1);                                           \
        Lacc[j] = __builtin_amdgcn_mfma_f32_16x16x32_bf16(pk.v, ones, Lacc[j],   \
                                                          0, 0, 0);              \
        for (int dt = 0; dt < 4; dt++)                                           \
          O[j][dt] = __builtin_amdgcn_mfma_f32_16x16x32_bf16(pk.v, vf[dt],       \
                                                             O[j][dt], 0, 0, 0); \
        __builtin_amdgcn_s_setprio(0);                                           \
      }                                                                          \
    }                                                                            \
  } while (0)

  STAGE_KV(0);
  for (int kt2 = 0; kt2 < 16; kt2++) {
    __syncthreads();   // buf0's loads visible; all waves done reading buf1
    STAGE_KV(1);       // tile 2*kt2+1 (always valid)
    COMPUTE(0);        // tile 2*kt2
    __syncthreads();   // buf1's loads visible; all waves done reading buf0
    if (kt2 < 15) STAGE_KV(0);  // tile 2*kt2+2
    COMPUTE(1);        // tile 2*kt2+1
  }
#undef STAGE_KV
#undef COMPUTE

  // epilogue: Lacc rows align with O rows -> no cross-lane traffic
  for (int j = 0; j < 2; j++) {
    for (int r = 0; r < 4; r++) {
      float inv = 1.f / Lacc[j][r];
      int row = b * T + q0 + w * 32 + j * 16 + quad * 4 + r;
      for (int dt = 0; dt < 4; dt++) {
        int col = h * 64 + dt * 16 + lr;
        y[(size_t)row * 1024 + col] = f2bf(O[j][dt][r] * inv);
      }
    }
  }
}

// ---------------- launch ----------------

extern "C" void kernel_launch(void* const* d_in, const int* in_sizes, int n_in,
                              void* d_out, int out_size, void* d_ws, size_t ws_size,
                              hipStream_t stream) {
  const float* x  = (const float*)d_in[0];
  const float* Wa = (const float*)d_in[1];
  const float* ba = (const float*)d_in[2];
  const float* Wp = (const float*)d_in[3];
  const float* bp = (const float*)d_in[4];
  float* out = (float*)d_out;

  char* ws = (char*)d_ws;
  unsigned short* xb  = (unsigned short*)ws;                 // 16 MB: x bf16, later y
  unsigned short* Wat = (unsigned short*)(ws + 16777216);    // 6 MB
  unsigned short* Wpt = (unsigned short*)(ws + 23068672);    // 2 MB
  unsigned short* qkv = (unsigned short*)(ws + 25165824);    // 48 MB (V third unused)
  unsigned short* vtr = (unsigned short*)(ws + 75497472);    // 16 MB

  cvt_x_bf16<<<8192, 256, 0, stream>>>(x, xb);
  transpose_w<<<dim3(96, 32), dim3(32, 8), 0, stream>>>(Wa, Wat, 1024, 3072);
  transpose_w<<<dim3(32, 32), dim3(32, 8), 0, stream>>>(Wp, Wpt, 1024, 1024);

  // 128^2 BK=64 gemm: QKV grid 64x24 = 1536 (6 full generations);
  // V third straight to vtr (transposed in-epilogue)
  gemm_bt<1><<<dim3(64, 24), 256, 0, stream>>>(xb, Wat, ba, qkv, vtr, 8192, 3072, 1024);

  attn_flash<<<1024, 256, 0, stream>>>(qkv, vtr, xb);

  gemm_bt<0><<<dim3(64, 8), 256, 0, stream>>>(xb, Wpt, bp, out, nullptr, 8192, 1024, 1024);
}